// Round 8
// baseline (205.715 us; speedup 1.0000x reference)
//
#include <hip/hip_runtime.h>

// Non-local (SAGAN) block on MI355X. B=8, C=256, C'=64, N=4096.
// Round 14: flash LDS cut to exactly 40KB -> 4 blocks/CU x 8 waves = 32
// waves/CU, grid 1024 = exactly 4/CU (zero tail). K single-buffered (mid-tile
// raw s_barrier + lgkmcnt(0), no vmcnt drain -> V prefetch stays in flight);
// Pb restrided 34->32 u32 with chunk-XOR swizzle (write & read same
// involution). memset dispatch deleted: qkv zero-fills Op+Lg at entry.
// ws: qT 4MB | kT 4MB | vB 4MB | Op[b][n][c'] f32 8MB | Lg[b][n] 128KB | Wb 128KB

#define Bsz 8
#define Cch 256
#define CPd 64
#define Nn  4096
#define TIL 64
#define QROWS 128              // flash Q rows per block (8 waves x 16)
#define NSPL 4                 // KV split factor
#define MQUAR (Nn / NSPL)      // 1024

typedef __attribute__((ext_vector_type(8))) short short8;   // 8 bf16 (MFMA A/B frag)
typedef __attribute__((ext_vector_type(4))) float f32x4;    // 16x16 C/D frag

static constexpr float C1 = (float)(1.41421 / 16.0);  // ROOT_2/sqrt(C)
static constexpr float C2 = (float)(1.41421 / 8.0);   // ROOT_2/sqrt(C')

__device__ inline unsigned pk_trunc(float lo, float hi) { // -> bf16x2 (truncate), 1 v_perm
    return __builtin_amdgcn_perm(__float_as_uint(hi), __float_as_uint(lo), 0x07060302u);
}
__device__ inline float dpp_swap1(float v) {  // lane l <-> l^1 (quad_perm [1,0,3,2])
    return __uint_as_float((unsigned)__builtin_amdgcn_mov_dpp(
        (int)__float_as_uint(v), 0xB1, 0xF, 0xF, true));
}
__device__ __forceinline__ void gl16(const unsigned short* g, unsigned short* s) {
    __builtin_amdgcn_global_load_lds(
        (const __attribute__((address_space(1))) void*)g,
        (__attribute__((address_space(3))) void*)s, 16, 0, 0);
}

// -------------------------------------------------------- W f32->bf16 conv --
__global__ __launch_bounds__(256) void wconv_kernel(
    const float* __restrict__ Wq, const float* __restrict__ Wk,
    const float* __restrict__ Wv, const float* __restrict__ Wo,
    unsigned short* __restrict__ Wb)
{
    const int idx = (blockIdx.x * 256 + threadIdx.x) * 4;   // grid 64 -> 65536 elements
    const float* src = (idx < 16384) ? Wq : (idx < 32768) ? Wk : (idx < 49152) ? Wv : Wo;
    const float4 v = *(const float4*)(src + (idx & 16383));
    *(uint2*)(Wb + idx) = make_uint2(pk_trunc(v.x, v.y), pk_trunc(v.z, v.w));
}

// --------------------------------------------------------- QKV proj (MFMA) --
// Also zero-fills Op+Lg (replaces the hipMemsetAsync dispatch).
__global__ __launch_bounds__(256) void qkv_kernel(
    const float* __restrict__ x, const unsigned short* __restrict__ Wb,
    const float* __restrict__ bq, const float* __restrict__ bk, const float* __restrict__ bv,
    unsigned short* __restrict__ qT, unsigned short* __restrict__ kT,
    unsigned short* __restrict__ vB, float* __restrict__ Opz)
{
    __shared__ __align__(16) unsigned short Wlds[CPd * 264];  // [o][c] bf16 (33 KB)
    __shared__ __align__(16) float T[TIL * 68];               // 17.4 KB

    const int b   = blockIdx.y;
    const int n0  = blockIdx.x * TIL;
    const int t   = threadIdx.x;
    const int g   = t >> 6;
    const int l15 = t & 15;
    const int l4  = (t & 63) >> 4;

    {   // zero Op+Lg accumulators: 532480 float4 over 131072 threads
        const int tid = (blockIdx.y * gridDim.x + blockIdx.x) * 256 + t;
        float4* z = (float4*)Opz;
        for (int i = tid; i < 532480; i += 131072)
            z[i] = make_float4(0.f, 0.f, 0.f, 0.f);
    }

    // A-frags from global x: lane row n = n0+16g+l15, k = c = 8*l4 + j + 32*ks
    const float* xb = x + (size_t)b * Cch * Nn + n0 + 16 * g + l15;
    short8 xf[8];
    #pragma unroll
    for (int ks = 0; ks < 8; ++ks) {
        float xr[8];
        #pragma unroll
        for (int j = 0; j < 8; ++j)
            xr[j] = C1 * xb[(size_t)(8 * l4 + 32 * ks + j) * Nn];
        union { unsigned u[4]; short8 s; } p;
        p.u[0] = pk_trunc(xr[0], xr[1]); p.u[1] = pk_trunc(xr[2], xr[3]);
        p.u[2] = pk_trunc(xr[4], xr[5]); p.u[3] = pk_trunc(xr[6], xr[7]);
        xf[ks] = p.s;
    }

    #pragma unroll
    for (int mat = 0; mat < 3; ++mat) {
        {   // stage W[64][256] bf16 = 2048 uint4, coalesced, 8 per thread
            const uint4* wg = (const uint4*)(Wb + mat * 16384);
            #pragma unroll
            for (int p = 0; p < 8; ++p) {
                const int idx = p * 256 + t;
                const int o = idx >> 5, cs = idx & 31;
                *(uint4*)&Wlds[o * 264 + cs * 8] = wg[idx];
            }
        }
        __syncthreads();   // W staged

        const float* bias = (mat == 0) ? bq : (mat == 1) ? bk : bv;
        f32x4 acc[4];
        #pragma unroll
        for (int st = 0; st < 4; ++st) {
            const float bb = bias[16 * st + l15];
            acc[st] = (f32x4){bb, bb, bb, bb};
        }
        #pragma unroll
        for (int st = 0; st < 4; ++st) {
            #pragma unroll
            for (int ks = 0; ks < 8; ++ks) {
                const short8 wf = *(const short8*)&Wlds[(16 * st + l15) * 264 + 8 * l4 + 32 * ks];
                acc[st] = __builtin_amdgcn_mfma_f32_16x16x32_bf16(xf[ks], wf, acc[st], 0, 0, 0);
            }
        }
        __syncthreads();   // all Wlds reads done (next mat may restage)

        if (mat < 2) {     // T as [n][c']
            #pragma unroll
            for (int st = 0; st < 4; ++st)
                #pragma unroll
                for (int r = 0; r < 4; ++r)
                    T[(16 * g + 4 * l4 + r) * 68 + 16 * st + l15] = acc[st][r];
        } else {           // v: T as [c'][n]
            #pragma unroll
            for (int st = 0; st < 4; ++st)
                #pragma unroll
                for (int r = 0; r < 4; ++r)
                    T[(16 * st + l15) * 68 + 16 * g + 4 * l4 + r] = acc[st][r];
        }
        __syncthreads();

        const int row = t >> 2;            // n (q/k) or c' (v)
        const int sg  = 16 * (t & 3);
        const float4 a0 = *(const float4*)&T[row * 68 + sg + 0];
        const float4 a1 = *(const float4*)&T[row * 68 + sg + 4];
        const float4 a2 = *(const float4*)&T[row * 68 + sg + 8];
        const float4 a3 = *(const float4*)&T[row * 68 + sg + 12];
        const uint4 lo = make_uint4(pk_trunc(a0.x, a0.y), pk_trunc(a0.z, a0.w),
                                    pk_trunc(a1.x, a1.y), pk_trunc(a1.z, a1.w));
        const uint4 hi = make_uint4(pk_trunc(a2.x, a2.y), pk_trunc(a2.z, a2.w),
                                    pk_trunc(a3.x, a3.y), pk_trunc(a3.z, a3.w));
        unsigned short* dst;
        if (mat < 2) {
            dst = (mat == 0 ? qT : kT) + ((size_t)(b * Nn + n0 + row)) * CPd + sg;
        } else {
            dst = vB + ((size_t)(b * CPd + row)) * Nn + n0 + sg;
        }
        *(uint4*)dst = lo;
        *(uint4*)(dst + 8) = hi;
    }
}

// ------------------------------------------------------------ flash (MFMA) --
// 8 waves x 16 Q-rows, LDS exactly 40KB -> 4 blocks/CU (grid 1024 = exactly
// 4/CU, zero tail). K single-buffered: QK -> lgkmcnt(0)+raw s_barrier (no
// vmcnt drain; V prefetch survives) -> restage K -> exp/pack -> PV ->
// __syncthreads (drains own gl16s). V double-buffered; Pb [128][32]u32 with
// chunk-XOR swizzle (^ row&7) on both write and read.
__global__ __launch_bounds__(512, 8) void flash_kernel(
    const unsigned short* __restrict__ qT, const unsigned short* __restrict__ kT,
    const unsigned short* __restrict__ vB, float* __restrict__ Op, float* __restrict__ Lg)
{
    __shared__ __align__(16) unsigned short Ks[TIL * 64];   // [m][c'] swizzled, 8 KB
    __shared__ __align__(16) unsigned short Vs0[TIL * 64];  // [c'][m] swizzled, 8 KB
    __shared__ __align__(16) unsigned short Vs1[TIL * 64];
    __shared__ __align__(16) unsigned Pb[QROWS * 32];       // bf16-pair, XOR-swz, 16 KB

    const int b   = blockIdx.y;
    const int n0  = blockIdx.x * QROWS;
    const int s   = blockIdx.z;
    const int t   = threadIdx.x;     // 0..511
    const int l   = t & 63;
    const int w   = t >> 6;          // 8 waves, 16 q-rows each
    const int l15 = l & 15;
    const int l4  = l >> 4;
    const int par = l & 1;
    const unsigned sel = par ? 0x03020706u : 0x07060302u;
    const int l15h = l15 >> 1;

    // Q A-frags straight from global
    const unsigned short* qp = qT + (size_t)(b * Nn + n0 + 16 * w + l15) * CPd + 8 * l4;
    const short8 qf0 = *(const short8*)qp;
    const short8 qf1 = *(const short8*)(qp + 32);

    f32x4 acco[4];
    #pragma unroll
    for (int ct = 0; ct < 4; ++ct) acco[ct] = (f32x4){0.f, 0.f, 0.f, 0.f};
    float Lp[4] = {0.f, 0.f, 0.f, 0.f};

    // staging geometry: wave w stages K rows [8w,8w+8) and V rows [8w,8w+8);
    // lane covers row 8w + (l>>3), LDS chunk l&7 <- source chunk (l&7)^(row&7)
    const int r8  = l >> 3;               // 0..7 (== row&7)
    const int sch = (l & 7) ^ r8;
    const unsigned short* kPtr = kT + (size_t)b * Nn * CPd
                               + (size_t)(8 * w + r8) * CPd + 8 * sch;
    const unsigned short* vPtr = vB + (size_t)b * CPd * Nn
                               + (size_t)(8 * w + r8) * Nn + 8 * sch;
    const int ldsOff = 8 * w * 64;        // wave-uniform LDS base (lane adds l*16B)

    // read-side swizzle: chunk c at row r lives at chunk c^(r&7)
    const int h7  = l15 & 7;
    const int sw0 = (l4 ^ h7) << 4;       // byte offset of chunk, ks=0 (ks=1: ^64)
    const char* KsB = (const char*)Ks + (l15 << 7);

    const int mbase = s * MQUAR;
    const int nt = MQUAR / TIL;           // 16

    auto STAGE_K = [&](int m0) { gl16(kPtr + (size_t)m0 * CPd, Ks + ldsOff); };
    auto STAGE_V = [&](unsigned short* VD, int m0) { gl16(vPtr + m0, VD + ldsOff); };

    STAGE_K(mbase);
    STAGE_V(Vs0, mbase);
    __syncthreads();                      // tile 0 staged (vmcnt drain + barrier)

    for (int ti = 0; ti < nt; ++ti) {
        const int m1 = mbase + (ti + 1) * TIL;
        if (ti + 1 < nt) STAGE_V(((ti + 1) & 1) ? Vs1 : Vs0, m1);  // prefetch V(ti+1)

        // ---- S = Q^T K: 4 chains x 2 k-steps, from the single K buffer ----
        f32x4 accs[4];
        __builtin_amdgcn_s_setprio(1);
        #pragma unroll
        for (int st = 0; st < 4; ++st) {
            accs[st] = (f32x4){0.f, 0.f, 0.f, 0.f};
            const short8 kf0 = *(const short8*)(KsB + (st << 11) + sw0);
            const short8 kf1 = *(const short8*)(KsB + (st << 11) + (sw0 ^ 64));
            accs[st] = __builtin_amdgcn_mfma_f32_16x16x32_bf16(qf0, kf0, accs[st], 0, 0, 0);
            accs[st] = __builtin_amdgcn_mfma_f32_16x16x32_bf16(qf1, kf1, accs[st], 0, 0, 0);
        }
        __builtin_amdgcn_s_setprio(0);

        // mid-tile: all waves' K reads retired; DO NOT drain vmcnt (V in flight)
        asm volatile("s_waitcnt lgkmcnt(0)" ::: "memory");
        __builtin_amdgcn_s_barrier();
        if (ti + 1 < nt) STAGE_K(m1);     // overwrite Ks; hidden under exp+PV

        // ---- P = exp(S) via __expf; DPP pair-pack; Pb chunk-XOR swizzle ----
        #pragma unroll
        for (int st = 0; st < 4; ++st) {
            unsigned u[4];
            #pragma unroll
            for (int r = 0; r < 4; ++r) {
                float p = __expf(accs[st][r]);
                Lp[r] += p;
                float nb = dpp_swap1(p);
                u[r] = __builtin_amdgcn_perm(__float_as_uint(nb), __float_as_uint(p), sel);
            }
            const int rb  = 16 * w + 4 * l4 + 2 * par; // even lane rows {0,1}; odd {2,3}
            const int ch  = 2 * st + (l15h >> 2);      // word>>2
            const int wic = l15h & 3;                  // word&3
            Pb[(rb + 0) * 32 + ((ch ^ ((rb)     & 7)) << 2) + wic] = u[2 * par];
            Pb[(rb + 1) * 32 + ((ch ^ ((rb + 1) & 7)) << 2) + wic] = u[2 * par + 1];
        }
        // no barrier: wave w reads only Pb rows [16w,16w+16) which it wrote

        // ---- O += P V^T ----
        const char* VsB = (const char*)((ti & 1) ? Vs1 : Vs0) + (l15 << 7);
        __builtin_amdgcn_s_setprio(1);
        #pragma unroll
        for (int ks = 0; ks < 2; ++ks) {
            const int pswz = ((l4 + 4 * ks) ^ h7) << 2;
            const short8 pf = *(const short8*)&Pb[(16 * w + l15) * 32 + pswz];
            const int swk = sw0 ^ (ks << 6);
            #pragma unroll
            for (int ct = 0; ct < 4; ++ct) {
                const short8 vf = *(const short8*)(VsB + (ct << 11) + swk);
                acco[ct] = __builtin_amdgcn_mfma_f32_16x16x32_bf16(pf, vf, acco[ct], 0, 0, 0);
            }
        }
        __builtin_amdgcn_s_setprio(0);

        __syncthreads();   // drains own gl16s (issued ~500cy ago); stages visible
    }

    // ---- epilogue: shuffle-reduce L over the 16 lanes of each row ----
    #pragma unroll
    for (int r = 0; r < 4; ++r) {
        float v = Lp[r];
        v += __shfl_xor(v, 1, 64); v += __shfl_xor(v, 2, 64);
        v += __shfl_xor(v, 4, 64); v += __shfl_xor(v, 8, 64);
        Lp[r] = v;
    }
    if (l15 == 0) {
        #pragma unroll
        for (int r = 0; r < 4; ++r)
            atomicAdd(&Lg[(size_t)b * Nn + n0 + 16 * w + 4 * l4 + r], Lp[r]);
    }
    float* ob = Op + ((size_t)(b * Nn + n0 + 16 * w)) * CPd;
    #pragma unroll
    for (int r = 0; r < 4; ++r) {
        const int nl = 4 * l4 + r;
        #pragma unroll
        for (int ct = 0; ct < 4; ++ct)
            atomicAdd(&ob[(size_t)nl * CPd + 16 * ct + l15], acco[ct][r]);
    }
}

// ------------------------------------------------------- output proj (MFMA) --
__global__ __launch_bounds__(512) void out_kernel(
    const float* __restrict__ Op, const float* __restrict__ Lg,
    const unsigned short* __restrict__ Wob,
    const float* __restrict__ bo, const float* __restrict__ gamma,
    const float* __restrict__ x, float* __restrict__ y)
{
    __shared__ __align__(16) unsigned short Wos[Cch * 72];  // 36 KB
    __shared__ __align__(16) unsigned short Sas[TIL * 72];  // 9 KB
    __shared__ float bos[Cch];

    const int b   = blockIdx.y;
    const int n0  = blockIdx.x * TIL;
    const int t   = threadIdx.x;     // 0..511
    const int l   = t & 63;
    const int w   = t >> 6;          // 8 waves
    const int l15 = l & 15;
    const int l4  = l >> 4;

    if (t < Cch) bos[t] = bo[t];
    {   // Wo bf16: 2048 uint4 / 512 threads = 4 each
        const uint4* wg = (const uint4*)Wob;
        #pragma unroll
        for (int p = 0; p < 4; ++p) {
            const int idx = p * 512 + t;
            const int row = idx >> 3, seg = idx & 7;
            *(uint4*)&Wos[row * 72 + seg * 8] = wg[idx];
        }
    }
    if (t < 256) {   // normalize accumulated partials + pack sa tile to bf16
        const int n = t >> 2, seg = t & 3;
        const float* o0 = Op + ((size_t)(b * Nn + n0 + n)) * CPd + seg * 16;
        const float sc = C2 / Lg[(size_t)b * Nn + n0 + n];
        unsigned pk[8];
        #pragma unroll
        for (int i = 0; i < 4; ++i) {
            const float4 a = ((const float4*)o0)[i];
            pk[2 * i]     = pk_trunc(a.x * sc, a.y * sc);
            pk[2 * i + 1] = pk_trunc(a.z * sc, a.w * sc);
        }
        *(uint4*)&Sas[n * 72 + seg * 16]     = make_uint4(pk[0], pk[1], pk[2], pk[3]);
        *(uint4*)&Sas[n * 72 + seg * 16 + 8] = make_uint4(pk[4], pk[5], pk[6], pk[7]);
    }
    __syncthreads();

    short8 bfr[4][2];
    #pragma unroll
    for (int ns = 0; ns < 4; ++ns) {
        bfr[ns][0] = *(const short8*)&Sas[(16 * ns + l15) * 72 + 8 * l4];
        bfr[ns][1] = *(const short8*)&Sas[(16 * ns + l15) * 72 + 8 * l4 + 32];
    }
    const float gam = gamma[0];
    const float* xb = x + (size_t)b * Cch * Nn;
    float*       yb = y + (size_t)b * Cch * Nn;

    #pragma unroll
    for (int os2 = 0; os2 < 2; ++os2) {
        const int obase = 16 * (w + 8 * os2);     // 16 strips over 8 waves x 2
        const short8 af0 = *(const short8*)&Wos[(obase + l15) * 72 + 8 * l4];
        const short8 af1 = *(const short8*)&Wos[(obase + l15) * 72 + 8 * l4 + 32];
        #pragma unroll
        for (int ns = 0; ns < 4; ++ns) {
            f32x4 acc = (f32x4){0.f, 0.f, 0.f, 0.f};
            acc = __builtin_amdgcn_mfma_f32_16x16x32_bf16(af0, bfr[ns][0], acc, 0, 0, 0);
            acc = __builtin_amdgcn_mfma_f32_16x16x32_bf16(af1, bfr[ns][1], acc, 0, 0, 0);
            #pragma unroll
            for (int r = 0; r < 4; ++r) {
                const int o = obase + 4 * l4 + r;
                const size_t idx = (size_t)o * Nn + n0 + 16 * ns + l15;
                yb[idx] = fmaf(gam, acc[r] + bos[o], xb[idx]);
            }
        }
    }
}

// ---------------------------------------------------------------------------
extern "C" void kernel_launch(void* const* d_in, const int* in_sizes, int n_in,
                              void* d_out, int out_size, void* d_ws, size_t ws_size,
                              hipStream_t stream)
{
    (void)in_sizes; (void)n_in; (void)out_size; (void)ws_size;
    const float* x     = (const float*)d_in[0];
    const float* Wq    = (const float*)d_in[1];
    const float* bq    = (const float*)d_in[2];
    const float* Wk    = (const float*)d_in[3];
    const float* bk    = (const float*)d_in[4];
    const float* Wv    = (const float*)d_in[5];
    const float* bv    = (const float*)d_in[6];
    const float* Wo    = (const float*)d_in[7];
    const float* bo    = (const float*)d_in[8];
    const float* gamma = (const float*)d_in[9];
    float* y = (float*)d_out;

    const size_t per = (size_t)Bsz * Nn * CPd;           // 2,097,152 elements
    unsigned short* qT = (unsigned short*)d_ws;          // 4 MB
    unsigned short* kT = qT + per;                       // 4 MB
    unsigned short* vB = kT + per;                       // 4 MB
    float* Op = (float*)(vB + per);                      // 8 MB: [b][n][c'] f32 accum
    float* Lg = Op + per;                                // 128 KB: [b][n] f32 accum
    unsigned short* Wb = (unsigned short*)(Lg + (size_t)Bsz * Nn);  // 128 KB

    dim3 grid(Nn / TIL, Bsz);
    dim3 gridF(Nn / QROWS, Bsz, NSPL);
    wconv_kernel<<<64, 256, 0, stream>>>(Wq, Wk, Wv, Wo, Wb);
    qkv_kernel<<<grid, 256, 0, stream>>>(x, Wb, bq, bk, bv, qT, kT, vB, Op);
    flash_kernel<<<gridF, 512, 0, stream>>>(qT, kT, vB, Op, Lg);
    out_kernel<<<grid, 512, 0, stream>>>(Op, Lg, Wb + 3 * 16384, bo, gamma, x, y);
}

// Round 9
// 182.209 us; speedup vs baseline: 1.1290x; 1.1290x over previous
//
#include <hip/hip_runtime.h>

// Non-local (SAGAN) block on MI355X. B=8, C=256, C'=64, N=4096.
// Round 15: flash/wconv/memset = R13-exact (proven 178.7us total, flash 66.4).
// qkv: blockIdx.z selects mat (q/k/v) -> 1536 blocks, 3x less serial chain,
// inner math identical. out: blockIdx.z selects o-half -> 1024 blocks,
// 27.6KB LDS, plain launch_bounds(512) (no VGPR clamp).
// ws: qT 4MB | kT 4MB | vB 4MB | Op[b][n][c'] f32 8MB | Lg[b][n] 128KB | Wb 128KB

#define Bsz 8
#define Cch 256
#define CPd 64
#define Nn  4096
#define TIL 64
#define QROWS 128              // flash Q rows per block (8 waves x 16)
#define NSPL 4                 // KV split factor
#define MQUAR (Nn / NSPL)      // 1024

typedef __attribute__((ext_vector_type(8))) short short8;   // 8 bf16 (MFMA A/B frag)
typedef __attribute__((ext_vector_type(4))) float f32x4;    // 16x16 C/D frag

static constexpr float C1 = (float)(1.41421 / 16.0);  // ROOT_2/sqrt(C)
static constexpr float C2 = (float)(1.41421 / 8.0);   // ROOT_2/sqrt(C')

__device__ inline unsigned pk_trunc(float lo, float hi) { // -> bf16x2 (truncate), 1 v_perm
    return __builtin_amdgcn_perm(__float_as_uint(hi), __float_as_uint(lo), 0x07060302u);
}
__device__ inline float dpp_swap1(float v) {  // lane l <-> l^1 (quad_perm [1,0,3,2])
    return __uint_as_float((unsigned)__builtin_amdgcn_mov_dpp(
        (int)__float_as_uint(v), 0xB1, 0xF, 0xF, true));
}
__device__ __forceinline__ void gl16(const unsigned short* g, unsigned short* s) {
    __builtin_amdgcn_global_load_lds(
        (const __attribute__((address_space(1))) void*)g,
        (__attribute__((address_space(3))) void*)s, 16, 0, 0);
}

// -------------------------------------------------------- W f32->bf16 conv --
__global__ __launch_bounds__(256) void wconv_kernel(
    const float* __restrict__ Wq, const float* __restrict__ Wk,
    const float* __restrict__ Wv, const float* __restrict__ Wo,
    unsigned short* __restrict__ Wb)
{
    const int idx = (blockIdx.x * 256 + threadIdx.x) * 4;   // grid 64 -> 65536 elements
    const float* src = (idx < 16384) ? Wq : (idx < 32768) ? Wk : (idx < 49152) ? Wv : Wo;
    const float4 v = *(const float4*)(src + (idx & 16383));
    *(uint2*)(Wb + idx) = make_uint2(pk_trunc(v.x, v.y), pk_trunc(v.z, v.w));
}

// --------------------------------------------------------- QKV proj (MFMA) --
// blockIdx.z = mat (0:q 1:k 2:v). Inner math identical to the proven 3-mat
// loop body; the serial chain per block is 1/3, block count 3x.
__global__ __launch_bounds__(256) void qkv_kernel(
    const float* __restrict__ x, const unsigned short* __restrict__ Wb,
    const float* __restrict__ bq, const float* __restrict__ bk, const float* __restrict__ bv,
    unsigned short* __restrict__ qT, unsigned short* __restrict__ kT,
    unsigned short* __restrict__ vB)
{
    __shared__ __align__(16) unsigned short Wlds[CPd * 264];  // [o][c] bf16 (33 KB)
    __shared__ __align__(16) float T[TIL * 68];               // 17.4 KB

    const int b   = blockIdx.y;
    const int n0  = blockIdx.x * TIL;
    const int mat = blockIdx.z;
    const int t   = threadIdx.x;
    const int g   = t >> 6;
    const int l15 = t & 15;
    const int l4  = (t & 63) >> 4;

    {   // stage W[64][256] bf16 = 2048 uint4, coalesced, 8 per thread
        const uint4* wg = (const uint4*)(Wb + mat * 16384);
        #pragma unroll
        for (int p = 0; p < 8; ++p) {
            const int idx = p * 256 + t;
            const int o = idx >> 5, cs = idx & 31;
            *(uint4*)&Wlds[o * 264 + cs * 8] = wg[idx];
        }
    }

    // A-frags from global x: lane row n = n0+16g+l15, k = c = 8*l4 + j + 32*ks
    const float* xb = x + (size_t)b * Cch * Nn + n0 + 16 * g + l15;
    short8 xf[8];
    #pragma unroll
    for (int ks = 0; ks < 8; ++ks) {
        float xr[8];
        #pragma unroll
        for (int j = 0; j < 8; ++j)
            xr[j] = C1 * xb[(size_t)(8 * l4 + 32 * ks + j) * Nn];
        union { unsigned u[4]; short8 s; } p;
        p.u[0] = pk_trunc(xr[0], xr[1]); p.u[1] = pk_trunc(xr[2], xr[3]);
        p.u[2] = pk_trunc(xr[4], xr[5]); p.u[3] = pk_trunc(xr[6], xr[7]);
        xf[ks] = p.s;
    }

    __syncthreads();   // W staged

    const float* bias = (mat == 0) ? bq : (mat == 1) ? bk : bv;
    f32x4 acc[4];
    #pragma unroll
    for (int st = 0; st < 4; ++st) {
        const float bb = bias[16 * st + l15];
        acc[st] = (f32x4){bb, bb, bb, bb};
    }
    #pragma unroll
    for (int st = 0; st < 4; ++st) {
        #pragma unroll
        for (int ks = 0; ks < 8; ++ks) {
            const short8 wf = *(const short8*)&Wlds[(16 * st + l15) * 264 + 8 * l4 + 32 * ks];
            acc[st] = __builtin_amdgcn_mfma_f32_16x16x32_bf16(xf[ks], wf, acc[st], 0, 0, 0);
        }
    }

    if (mat < 2) {     // T as [n][c']
        #pragma unroll
        for (int st = 0; st < 4; ++st)
            #pragma unroll
            for (int r = 0; r < 4; ++r)
                T[(16 * g + 4 * l4 + r) * 68 + 16 * st + l15] = acc[st][r];
    } else {           // v: T as [c'][n]
        #pragma unroll
        for (int st = 0; st < 4; ++st)
            #pragma unroll
            for (int r = 0; r < 4; ++r)
                T[(16 * st + l15) * 68 + 16 * g + 4 * l4 + r] = acc[st][r];
    }
    __syncthreads();   // T visible

    const int row = t >> 2;            // n (q/k) or c' (v)
    const int sg  = 16 * (t & 3);
    const float4 a0 = *(const float4*)&T[row * 68 + sg + 0];
    const float4 a1 = *(const float4*)&T[row * 68 + sg + 4];
    const float4 a2 = *(const float4*)&T[row * 68 + sg + 8];
    const float4 a3 = *(const float4*)&T[row * 68 + sg + 12];
    const uint4 lo = make_uint4(pk_trunc(a0.x, a0.y), pk_trunc(a0.z, a0.w),
                                pk_trunc(a1.x, a1.y), pk_trunc(a1.z, a1.w));
    const uint4 hi = make_uint4(pk_trunc(a2.x, a2.y), pk_trunc(a2.z, a2.w),
                                pk_trunc(a3.x, a3.y), pk_trunc(a3.z, a3.w));
    unsigned short* dst;
    if (mat < 2) {
        dst = (mat == 0 ? qT : kT) + ((size_t)(b * Nn + n0 + row)) * CPd + sg;
    } else {
        dst = vB + ((size_t)(b * CPd + row)) * Nn + n0 + sg;
    }
    *(uint4*)dst = lo;
    *(uint4*)(dst + 8) = hi;
}

// ------------------------------------------------------------ flash (MFMA) --
// R13-exact (proven 66.4us): 8 waves x 16 Q-rows, K/V double-buffered in four
// statically-named LDS arrays, STAGE(next) before COMPUTE(cur), one
// __syncthreads per tile, P wave-private, __expf, setprio around MFMA.
__global__ __launch_bounds__(512, 6) void flash_kernel(
    const unsigned short* __restrict__ qT, const unsigned short* __restrict__ kT,
    const unsigned short* __restrict__ vB, float* __restrict__ Op, float* __restrict__ Lg)
{
    __shared__ __align__(16) unsigned short Ks0[TIL * 64];  // [m][c'] swizzled, 8 KB
    __shared__ __align__(16) unsigned short Ks1[TIL * 64];
    __shared__ __align__(16) unsigned short Vs0[TIL * 64];  // [c'][m] swizzled, 8 KB
    __shared__ __align__(16) unsigned short Vs1[TIL * 64];
    __shared__ __align__(16) unsigned Pb[QROWS * 34];       // bf16-pair [n][m/2], 17.4 KB

    const int b   = blockIdx.y;
    const int n0  = blockIdx.x * QROWS;
    const int s   = blockIdx.z;
    const int t   = threadIdx.x;     // 0..511
    const int l   = t & 63;
    const int w   = t >> 6;          // 8 waves, 16 q-rows each
    const int l15 = l & 15;
    const int l4  = l >> 4;
    const int par = l & 1;
    const unsigned sel = par ? 0x03020706u : 0x07060302u;
    const int l15h = l15 >> 1;

    // Q A-frags straight from global
    const unsigned short* qp = qT + (size_t)(b * Nn + n0 + 16 * w + l15) * CPd + 8 * l4;
    const short8 qf0 = *(const short8*)qp;
    const short8 qf1 = *(const short8*)(qp + 32);

    f32x4 acco[4];
    #pragma unroll
    for (int ct = 0; ct < 4; ++ct) acco[ct] = (f32x4){0.f, 0.f, 0.f, 0.f};
    float Lp[4] = {0.f, 0.f, 0.f, 0.f};

    // staging geometry: wave w stages K rows [8w,8w+8) and V rows [8w,8w+8);
    // lane covers row 8w + (l>>3), LDS chunk l&7 <- source chunk (l&7)^(row&7)
    const int r8  = l >> 3;               // 0..7 (== row&7)
    const int sch = (l & 7) ^ r8;
    const unsigned short* kPtr = kT + (size_t)b * Nn * CPd
                               + (size_t)(8 * w + r8) * CPd + 8 * sch;
    const unsigned short* vPtr = vB + (size_t)b * CPd * Nn
                               + (size_t)(8 * w + r8) * Nn + 8 * sch;
    const int ldsOff = 8 * w * 64;        // wave-uniform LDS base (lane adds l*16B)

    // read-side swizzle: chunk c at row r lives at chunk c^(r&7)
    const int h7  = l15 & 7;
    const int sw0 = (l4 ^ h7) << 4;       // byte offset of chunk, ks=0 (ks=1: ^64)

    const int mbase = s * MQUAR;
    const int nt = MQUAR / TIL;           // 16 (even)

    auto STAGE = [&](unsigned short* KD, unsigned short* VD, int m0) {
        gl16(kPtr + (size_t)m0 * CPd, KD + ldsOff);
        gl16(vPtr + m0,               VD + ldsOff);
    };
    auto COMPUTE = [&](const unsigned short* Kb, const unsigned short* Vb) {
        const char* KsB = (const char*)Kb + (l15 << 7);
        const char* VsB = (const char*)Vb + (l15 << 7);
        // ---- S = Q^T K: 4 chains x 2 k-steps ----
        f32x4 accs[4];
        __builtin_amdgcn_s_setprio(1);
        #pragma unroll
        for (int st = 0; st < 4; ++st) {
            accs[st] = (f32x4){0.f, 0.f, 0.f, 0.f};
            const short8 kf0 = *(const short8*)(KsB + (st << 11) + sw0);
            const short8 kf1 = *(const short8*)(KsB + (st << 11) + (sw0 ^ 64));
            accs[st] = __builtin_amdgcn_mfma_f32_16x16x32_bf16(qf0, kf0, accs[st], 0, 0, 0);
            accs[st] = __builtin_amdgcn_mfma_f32_16x16x32_bf16(qf1, kf1, accs[st], 0, 0, 0);
        }
        __builtin_amdgcn_s_setprio(0);
        // ---- P = exp(S) via __expf (v_mul+v_exp); DPP pair-pack to bf16 ----
        #pragma unroll
        for (int st = 0; st < 4; ++st) {
            unsigned u[4];
            #pragma unroll
            for (int r = 0; r < 4; ++r) {
                float p = __expf(accs[st][r]);
                Lp[r] += p;
                float nb = dpp_swap1(p);
                u[r] = __builtin_amdgcn_perm(__float_as_uint(nb), __float_as_uint(p), sel);
            }
            const int rb = 16 * w + 4 * l4 + 2 * par;  // even lane: rows {0,1}; odd: {2,3}
            Pb[(rb + 0) * 34 + 8 * st + l15h] = u[2 * par];
            Pb[(rb + 1) * 34 + 8 * st + l15h] = u[2 * par + 1];
        }
        // no barrier: wave w reads only Pb rows [16w,16w+16) which it wrote
        __builtin_amdgcn_s_setprio(1);
        #pragma unroll
        for (int ks = 0; ks < 2; ++ks) {
            const short8 pf = *(const short8*)&Pb[(16 * w + l15) * 34 + 4 * l4 + 16 * ks];
            const int swk = sw0 ^ (ks << 6);
            #pragma unroll
            for (int ct = 0; ct < 4; ++ct) {
                const short8 vf = *(const short8*)(VsB + (ct << 11) + swk);
                acco[ct] = __builtin_amdgcn_mfma_f32_16x16x32_bf16(pf, vf, acco[ct], 0, 0, 0);
            }
        }
        __builtin_amdgcn_s_setprio(0);
    };

    STAGE(Ks0, Vs0, mbase);
    __syncthreads();                      // buf0 staged (vmcnt drain + barrier)
    for (int ti = 0; ti < nt; ti += 2) {
        const int m0 = mbase + ti * TIL;
        STAGE(Ks1, Vs1, m0 + TIL);        // issue early: hides under compute
        COMPUTE(Ks0, Vs0);
        __syncthreads();                  // drains (cheap: issued ~1500cy ago); fences buf0
        if (ti + 2 < nt) STAGE(Ks0, Vs0, m0 + 2 * TIL);
        COMPUTE(Ks1, Vs1);
        __syncthreads();
    }

    // ---- epilogue: shuffle-reduce L over the 16 lanes of each row ----
    #pragma unroll
    for (int r = 0; r < 4; ++r) {
        float v = Lp[r];
        v += __shfl_xor(v, 1, 64); v += __shfl_xor(v, 2, 64);
        v += __shfl_xor(v, 4, 64); v += __shfl_xor(v, 8, 64);
        Lp[r] = v;
    }
    if (l15 == 0) {
        #pragma unroll
        for (int r = 0; r < 4; ++r)
            atomicAdd(&Lg[(size_t)b * Nn + n0 + 16 * w + 4 * l4 + r], Lp[r]);
    }
    float* ob = Op + ((size_t)(b * Nn + n0 + 16 * w)) * CPd;
    #pragma unroll
    for (int r = 0; r < 4; ++r) {
        const int nl = 4 * l4 + r;
        #pragma unroll
        for (int ct = 0; ct < 4; ++ct)
            atomicAdd(&ob[(size_t)nl * CPd + 16 * ct + l15], acco[ct][r]);
    }
}

// ------------------------------------------------------- output proj (MFMA) --
// blockIdx.z = o-half. Each block stages 128 rows of Wo (18KB) and computes
// 128o x 64n. Plain launch_bounds(512) (no min-wave VGPR clamp).
__global__ __launch_bounds__(512) void out_kernel(
    const float* __restrict__ Op, const float* __restrict__ Lg,
    const unsigned short* __restrict__ Wob,
    const float* __restrict__ bo, const float* __restrict__ gamma,
    const float* __restrict__ x, float* __restrict__ y)
{
    __shared__ __align__(16) unsigned short Wos[128 * 72];  // 18 KB
    __shared__ __align__(16) unsigned short Sas[TIL * 72];  // 9 KB
    __shared__ float bos[128];

    const int b   = blockIdx.y;
    const int n0  = blockIdx.x * TIL;
    const int oz  = blockIdx.z;      // o-half
    const int t   = threadIdx.x;     // 0..511
    const int l   = t & 63;
    const int w   = t >> 6;          // 8 waves -> 8 o-strips of 16
    const int l15 = l & 15;
    const int l4  = l >> 4;

    if (t < 128) bos[t] = bo[128 * oz + t];
    {   // half Wo bf16: 1024 uint4 / 512 threads = 2 each
        const uint4* wg = (const uint4*)Wob + 1024 * oz;
        #pragma unroll
        for (int p = 0; p < 2; ++p) {
            const int idx = p * 512 + t;
            const int row = idx >> 3, seg = idx & 7;
            *(uint4*)&Wos[row * 72 + seg * 8] = wg[idx];
        }
    }
    if (t < 256) {   // normalize accumulated partials + pack sa tile to bf16
        const int n = t >> 2, seg = t & 3;
        const float* o0 = Op + ((size_t)(b * Nn + n0 + n)) * CPd + seg * 16;
        const float sc = C2 / Lg[(size_t)b * Nn + n0 + n];
        unsigned pk[8];
        #pragma unroll
        for (int i = 0; i < 4; ++i) {
            const float4 a = ((const float4*)o0)[i];
            pk[2 * i]     = pk_trunc(a.x * sc, a.y * sc);
            pk[2 * i + 1] = pk_trunc(a.z * sc, a.w * sc);
        }
        *(uint4*)&Sas[n * 72 + seg * 16]     = make_uint4(pk[0], pk[1], pk[2], pk[3]);
        *(uint4*)&Sas[n * 72 + seg * 16 + 8] = make_uint4(pk[4], pk[5], pk[6], pk[7]);
    }
    __syncthreads();

    const float gam = gamma[0];
    const float* xb = x + (size_t)(b * Cch + 128 * oz) * Nn;
    float*       yb = y + (size_t)(b * Cch + 128 * oz) * Nn;

    const int obase = 16 * w;        // local o-strip
    const short8 af0 = *(const short8*)&Wos[(obase + l15) * 72 + 8 * l4];
    const short8 af1 = *(const short8*)&Wos[(obase + l15) * 72 + 8 * l4 + 32];
    #pragma unroll
    for (int ns = 0; ns < 4; ++ns) {
        const short8 b0 = *(const short8*)&Sas[(16 * ns + l15) * 72 + 8 * l4];
        const short8 b1 = *(const short8*)&Sas[(16 * ns + l15) * 72 + 8 * l4 + 32];
        f32x4 acc = (f32x4){0.f, 0.f, 0.f, 0.f};
        acc = __builtin_amdgcn_mfma_f32_16x16x32_bf16(af0, b0, acc, 0, 0, 0);
        acc = __builtin_amdgcn_mfma_f32_16x16x32_bf16(af1, b1, acc, 0, 0, 0);
        #pragma unroll
        for (int r = 0; r < 4; ++r) {
            const int ol = obase + 4 * l4 + r;           // local o (0..127)
            const size_t idx = (size_t)ol * Nn + n0 + 16 * ns + l15;
            yb[idx] = fmaf(gam, acc[r] + bos[ol], xb[idx]);
        }
    }
}

// ---------------------------------------------------------------------------
extern "C" void kernel_launch(void* const* d_in, const int* in_sizes, int n_in,
                              void* d_out, int out_size, void* d_ws, size_t ws_size,
                              hipStream_t stream)
{
    (void)in_sizes; (void)n_in; (void)out_size; (void)ws_size;
    const float* x     = (const float*)d_in[0];
    const float* Wq    = (const float*)d_in[1];
    const float* bq    = (const float*)d_in[2];
    const float* Wk    = (const float*)d_in[3];
    const float* bk    = (const float*)d_in[4];
    const float* Wv    = (const float*)d_in[5];
    const float* bv    = (const float*)d_in[6];
    const float* Wo    = (const float*)d_in[7];
    const float* bo    = (const float*)d_in[8];
    const float* gamma = (const float*)d_in[9];
    float* y = (float*)d_out;

    const size_t per = (size_t)Bsz * Nn * CPd;           // 2,097,152 elements
    unsigned short* qT = (unsigned short*)d_ws;          // 4 MB
    unsigned short* kT = qT + per;                       // 4 MB
    unsigned short* vB = kT + per;                       // 4 MB
    float* Op = (float*)(vB + per);                      // 8 MB: [b][n][c'] f32 accum
    float* Lg = Op + per;                                // 128 KB: [b][n] f32 accum
    unsigned short* Wb = (unsigned short*)(Lg + (size_t)Bsz * Nn);  // 128 KB

    // zero the atomically-accumulated partials (Op + Lg are contiguous)
    hipMemsetAsync(Op, 0, (per + (size_t)Bsz * Nn) * sizeof(float), stream);

    dim3 gridQ(Nn / TIL, Bsz, 3);
    dim3 gridO(Nn / TIL, Bsz, 2);
    dim3 gridF(Nn / QROWS, Bsz, NSPL);
    wconv_kernel<<<64, 256, 0, stream>>>(Wq, Wk, Wv, Wo, Wb);
    qkv_kernel<<<gridQ, 256, 0, stream>>>(x, Wb, bq, bk, bv, qT, kT, vB);
    flash_kernel<<<gridF, 512, 0, stream>>>(qT, kT, vB, Op, Lg);
    out_kernel<<<gridO, 512, 0, stream>>>(Op, Lg, Wb + 3 * 16384, bo, gamma, x, y);
}

// Round 11
// 178.972 us; speedup vs baseline: 1.1494x; 1.0181x over previous
//
#include <hip/hip_runtime.h>

// Non-local (SAGAN) block on MI355X. B=8, C=256, C'=64, N=4096.
// Round 17 (= R16 resubmit, de-bundled after infra double-failure):
// base = R13 (proven 178.7us total, flash 66.4-67.2). Single delta:
//  - flash: T1 bijective XCD swizzle lg=(hw&7)*128+(hw>>3) so all 32
//    n0-siblings of one (b,s) K/V stream co-reside on one XCD's L2.
// wconv/qkv/out/memset = R13-exact.
// ws: qT 4MB | kT 4MB | vB 4MB | Op[b][n][c'] f32 8MB | Lg[b][n] 128KB | Wb 128KB

#define Bsz 8
#define Cch 256
#define CPd 64
#define Nn  4096
#define TIL 64
#define QROWS 128              // flash Q rows per block (8 waves x 16)
#define NSPL 4                 // KV split factor
#define MQUAR (Nn / NSPL)      // 1024

typedef __attribute__((ext_vector_type(8))) short short8;   // 8 bf16 (MFMA A/B frag)
typedef __attribute__((ext_vector_type(4))) float f32x4;    // 16x16 C/D frag

static constexpr float C1 = (float)(1.41421 / 16.0);  // ROOT_2/sqrt(C)
static constexpr float C2 = (float)(1.41421 / 8.0);   // ROOT_2/sqrt(C')

__device__ inline unsigned pk_trunc(float lo, float hi) { // -> bf16x2 (truncate), 1 v_perm
    return __builtin_amdgcn_perm(__float_as_uint(hi), __float_as_uint(lo), 0x07060302u);
}
__device__ inline float dpp_swap1(float v) {  // lane l <-> l^1 (quad_perm [1,0,3,2])
    return __uint_as_float((unsigned)__builtin_amdgcn_mov_dpp(
        (int)__float_as_uint(v), 0xB1, 0xF, 0xF, true));
}
__device__ __forceinline__ void gl16(const unsigned short* g, unsigned short* s) {
    __builtin_amdgcn_global_load_lds(
        (const __attribute__((address_space(1))) void*)g,
        (__attribute__((address_space(3))) void*)s, 16, 0, 0);
}

// -------------------------------------------------------- W f32->bf16 conv --
__global__ __launch_bounds__(256) void wconv_kernel(
    const float* __restrict__ Wq, const float* __restrict__ Wk,
    const float* __restrict__ Wv, const float* __restrict__ Wo,
    unsigned short* __restrict__ Wb)
{
    const int idx = (blockIdx.x * 256 + threadIdx.x) * 4;   // grid 64 -> 65536 elements
    const float* src = (idx < 16384) ? Wq : (idx < 32768) ? Wk : (idx < 49152) ? Wv : Wo;
    const float4 v = *(const float4*)(src + (idx & 16383));
    *(uint2*)(Wb + idx) = make_uint2(pk_trunc(v.x, v.y), pk_trunc(v.z, v.w));
}

// --------------------------------------------------------- QKV proj (MFMA) --
__global__ __launch_bounds__(256) void qkv_kernel(
    const float* __restrict__ x, const unsigned short* __restrict__ Wb,
    const float* __restrict__ bq, const float* __restrict__ bk, const float* __restrict__ bv,
    unsigned short* __restrict__ qT, unsigned short* __restrict__ kT,
    unsigned short* __restrict__ vB)
{
    __shared__ __align__(16) unsigned short Wlds[CPd * 264];  // [o][c] bf16 (33 KB)
    __shared__ __align__(16) float T[TIL * 68];               // 17.4 KB

    const int b   = blockIdx.y;
    const int n0  = blockIdx.x * TIL;
    const int t   = threadIdx.x;
    const int g   = t >> 6;
    const int l15 = t & 15;
    const int l4  = (t & 63) >> 4;

    // A-frags from global x: lane row n = n0+16g+l15, k = c = 8*l4 + j + 32*ks
    const float* xb = x + (size_t)b * Cch * Nn + n0 + 16 * g + l15;
    short8 xf[8];
    #pragma unroll
    for (int ks = 0; ks < 8; ++ks) {
        float xr[8];
        #pragma unroll
        for (int j = 0; j < 8; ++j)
            xr[j] = C1 * xb[(size_t)(8 * l4 + 32 * ks + j) * Nn];
        union { unsigned u[4]; short8 s; } p;
        p.u[0] = pk_trunc(xr[0], xr[1]); p.u[1] = pk_trunc(xr[2], xr[3]);
        p.u[2] = pk_trunc(xr[4], xr[5]); p.u[3] = pk_trunc(xr[6], xr[7]);
        xf[ks] = p.s;
    }

    #pragma unroll
    for (int mat = 0; mat < 3; ++mat) {
        {   // stage W[64][256] bf16 = 2048 uint4, coalesced, 8 per thread
            const uint4* wg = (const uint4*)(Wb + mat * 16384);
            #pragma unroll
            for (int p = 0; p < 8; ++p) {
                const int idx = p * 256 + t;
                const int o = idx >> 5, cs = idx & 31;
                *(uint4*)&Wlds[o * 264 + cs * 8] = wg[idx];
            }
        }
        __syncthreads();   // W staged

        const float* bias = (mat == 0) ? bq : (mat == 1) ? bk : bv;
        f32x4 acc[4];
        #pragma unroll
        for (int st = 0; st < 4; ++st) {
            const float bb = bias[16 * st + l15];
            acc[st] = (f32x4){bb, bb, bb, bb};
        }
        #pragma unroll
        for (int st = 0; st < 4; ++st) {
            #pragma unroll
            for (int ks = 0; ks < 8; ++ks) {
                const short8 wf = *(const short8*)&Wlds[(16 * st + l15) * 264 + 8 * l4 + 32 * ks];
                acc[st] = __builtin_amdgcn_mfma_f32_16x16x32_bf16(xf[ks], wf, acc[st], 0, 0, 0);
            }
        }
        __syncthreads();   // all Wlds reads done (next mat may restage)

        if (mat < 2) {     // T as [n][c']
            #pragma unroll
            for (int st = 0; st < 4; ++st)
                #pragma unroll
                for (int r = 0; r < 4; ++r)
                    T[(16 * g + 4 * l4 + r) * 68 + 16 * st + l15] = acc[st][r];
        } else {           // v: T as [c'][n]
            #pragma unroll
            for (int st = 0; st < 4; ++st)
                #pragma unroll
                for (int r = 0; r < 4; ++r)
                    T[(16 * st + l15) * 68 + 16 * g + 4 * l4 + r] = acc[st][r];
        }
        __syncthreads();

        const int row = t >> 2;            // n (q/k) or c' (v)
        const int sg  = 16 * (t & 3);
        const float4 a0 = *(const float4*)&T[row * 68 + sg + 0];
        const float4 a1 = *(const float4*)&T[row * 68 + sg + 4];
        const float4 a2 = *(const float4*)&T[row * 68 + sg + 8];
        const float4 a3 = *(const float4*)&T[row * 68 + sg + 12];
        const uint4 lo = make_uint4(pk_trunc(a0.x, a0.y), pk_trunc(a0.z, a0.w),
                                    pk_trunc(a1.x, a1.y), pk_trunc(a1.z, a1.w));
        const uint4 hi = make_uint4(pk_trunc(a2.x, a2.y), pk_trunc(a2.z, a2.w),
                                    pk_trunc(a3.x, a3.y), pk_trunc(a3.z, a3.w));
        unsigned short* dst;
        if (mat < 2) {
            dst = (mat == 0 ? qT : kT) + ((size_t)(b * Nn + n0 + row)) * CPd + sg;
        } else {
            dst = vB + ((size_t)(b * CPd + row)) * Nn + n0 + sg;
        }
        *(uint4*)dst = lo;
        *(uint4*)(dst + 8) = hi;
    }
}

// ------------------------------------------------------------ flash (MFMA) --
// R13 structure + T1 XCD swizzle: hw linear id -> lg=(hw&7)*128+(hw>>3)
// (bijective, nwg=1024, 128 contiguous logical ids per XCD = 4 full (b,s)
// groups -> K/V streams L2-resident). Rest identical to proven R13.
__global__ __launch_bounds__(512, 6) void flash_kernel(
    const unsigned short* __restrict__ qT, const unsigned short* __restrict__ kT,
    const unsigned short* __restrict__ vB, float* __restrict__ Op, float* __restrict__ Lg)
{
    __shared__ __align__(16) unsigned short Ks0[TIL * 64];  // [m][c'] swizzled, 8 KB
    __shared__ __align__(16) unsigned short Ks1[TIL * 64];
    __shared__ __align__(16) unsigned short Vs0[TIL * 64];  // [c'][m] swizzled, 8 KB
    __shared__ __align__(16) unsigned short Vs1[TIL * 64];
    __shared__ __align__(16) unsigned Pb[QROWS * 34];       // bf16-pair [n][m/2], 17.4 KB

    // T1: bijective XCD remap (1024 blocks, 8 XCDs, 128 per XCD)
    const int hw  = blockIdx.x + 32 * (blockIdx.y + 8 * blockIdx.z);
    const int lg  = (hw & 7) * 128 + (hw >> 3);
    const int n0  = (lg & 31) * QROWS;   // 32 n0-tiles
    const int b   = (lg >> 5) & 7;
    const int s   = lg >> 8;

    const int t   = threadIdx.x;     // 0..511
    const int l   = t & 63;
    const int w   = t >> 6;          // 8 waves, 16 q-rows each
    const int l15 = l & 15;
    const int l4  = l >> 4;
    const int par = l & 1;
    const unsigned sel = par ? 0x03020706u : 0x07060302u;
    const int l15h = l15 >> 1;

    // Q A-frags straight from global
    const unsigned short* qp = qT + (size_t)(b * Nn + n0 + 16 * w + l15) * CPd + 8 * l4;
    const short8 qf0 = *(const short8*)qp;
    const short8 qf1 = *(const short8*)(qp + 32);

    f32x4 acco[4];
    #pragma unroll
    for (int ct = 0; ct < 4; ++ct) acco[ct] = (f32x4){0.f, 0.f, 0.f, 0.f};
    float Lp[4] = {0.f, 0.f, 0.f, 0.f};

    // staging geometry: wave w stages K rows [8w,8w+8) and V rows [8w,8w+8);
    // lane covers row 8w + (l>>3), LDS chunk l&7 <- source chunk (l&7)^(row&7)
    const int r8  = l >> 3;               // 0..7 (== row&7)
    const int sch = (l & 7) ^ r8;
    const unsigned short* kPtr = kT + (size_t)b * Nn * CPd
                               + (size_t)(8 * w + r8) * CPd + 8 * sch;
    const unsigned short* vPtr = vB + (size_t)b * CPd * Nn
                               + (size_t)(8 * w + r8) * Nn + 8 * sch;
    const int ldsOff = 8 * w * 64;        // wave-uniform LDS base (lane adds l*16B)

    // read-side swizzle: chunk c at row r lives at chunk c^(r&7)
    const int h7  = l15 & 7;
    const int sw0 = (l4 ^ h7) << 4;       // byte offset of chunk, ks=0 (ks=1: ^64)

    const int mbase = s * MQUAR;
    const int nt = MQUAR / TIL;           // 16 (even)

    auto STAGE = [&](unsigned short* KD, unsigned short* VD, int m0) {
        gl16(kPtr + (size_t)m0 * CPd, KD + ldsOff);
        gl16(vPtr + m0,               VD + ldsOff);
    };
    auto COMPUTE = [&](const unsigned short* Kb, const unsigned short* Vb) {
        const char* KsB = (const char*)Kb + (l15 << 7);
        const char* VsB = (const char*)Vb + (l15 << 7);
        // ---- S = Q^T K: 4 chains x 2 k-steps ----
        f32x4 accs[4];
        __builtin_amdgcn_s_setprio(1);
        #pragma unroll
        for (int st = 0; st < 4; ++st) {
            accs[st] = (f32x4){0.f, 0.f, 0.f, 0.f};
            const short8 kf0 = *(const short8*)(KsB + (st << 11) + sw0);
            const short8 kf1 = *(const short8*)(KsB + (st << 11) + (sw0 ^ 64));
            accs[st] = __builtin_amdgcn_mfma_f32_16x16x32_bf16(qf0, kf0, accs[st], 0, 0, 0);
            accs[st] = __builtin_amdgcn_mfma_f32_16x16x32_bf16(qf1, kf1, accs[st], 0, 0, 0);
        }
        __builtin_amdgcn_s_setprio(0);
        // ---- P = exp(S) via __expf (v_mul+v_exp); DPP pair-pack to bf16 ----
        #pragma unroll
        for (int st = 0; st < 4; ++st) {
            unsigned u[4];
            #pragma unroll
            for (int r = 0; r < 4; ++r) {
                float p = __expf(accs[st][r]);
                Lp[r] += p;
                float nb = dpp_swap1(p);
                u[r] = __builtin_amdgcn_perm(__float_as_uint(nb), __float_as_uint(p), sel);
            }
            const int rb = 16 * w + 4 * l4 + 2 * par;  // even lane: rows {0,1}; odd: {2,3}
            Pb[(rb + 0) * 34 + 8 * st + l15h] = u[2 * par];
            Pb[(rb + 1) * 34 + 8 * st + l15h] = u[2 * par + 1];
        }
        // no barrier: wave w reads only Pb rows [16w,16w+16) which it wrote
        __builtin_amdgcn_s_setprio(1);
        #pragma unroll
        for (int ks = 0; ks < 2; ++ks) {
            const short8 pf = *(const short8*)&Pb[(16 * w + l15) * 34 + 4 * l4 + 16 * ks];
            const int swk = sw0 ^ (ks << 6);
            #pragma unroll
            for (int ct = 0; ct < 4; ++ct) {
                const short8 vf = *(const short8*)(VsB + (ct << 11) + swk);
                acco[ct] = __builtin_amdgcn_mfma_f32_16x16x32_bf16(pf, vf, acco[ct], 0, 0, 0);
            }
        }
        __builtin_amdgcn_s_setprio(0);
    };

    STAGE(Ks0, Vs0, mbase);
    __syncthreads();                      // buf0 staged (vmcnt drain + barrier)
    for (int ti = 0; ti < nt; ti += 2) {
        const int m0 = mbase + ti * TIL;
        STAGE(Ks1, Vs1, m0 + TIL);        // issue early: hides under compute
        COMPUTE(Ks0, Vs0);
        __syncthreads();                  // drains (cheap: issued ~1500cy ago); fences buf0
        if (ti + 2 < nt) STAGE(Ks0, Vs0, m0 + 2 * TIL);
        COMPUTE(Ks1, Vs1);
        __syncthreads();
    }

    // ---- epilogue: shuffle-reduce L over the 16 lanes of each row ----
    #pragma unroll
    for (int r = 0; r < 4; ++r) {
        float v = Lp[r];
        v += __shfl_xor(v, 1, 64); v += __shfl_xor(v, 2, 64);
        v += __shfl_xor(v, 4, 64); v += __shfl_xor(v, 8, 64);
        Lp[r] = v;
    }
    if (l15 == 0) {
        #pragma unroll
        for (int r = 0; r < 4; ++r)
            atomicAdd(&Lg[(size_t)b * Nn + n0 + 16 * w + 4 * l4 + r], Lp[r]);
    }
    float* ob = Op + ((size_t)(b * Nn + n0 + 16 * w)) * CPd;
    #pragma unroll
    for (int r = 0; r < 4; ++r) {
        const int nl = 4 * l4 + r;
        #pragma unroll
        for (int ct = 0; ct < 4; ++ct)
            atomicAdd(&ob[(size_t)nl * CPd + 16 * ct + l15], acco[ct][r]);
    }
}

// ------------------------------------------------------- output proj (MFMA) --
__global__ __launch_bounds__(512) void out_kernel(
    const float* __restrict__ Op, const float* __restrict__ Lg,
    const unsigned short* __restrict__ Wob,
    const float* __restrict__ bo, const float* __restrict__ gamma,
    const float* __restrict__ x, float* __restrict__ y)
{
    __shared__ __align__(16) unsigned short Wos[Cch * 72];  // 36 KB
    __shared__ __align__(16) unsigned short Sas[TIL * 72];  // 9 KB
    __shared__ float bos[Cch];

    const int b   = blockIdx.y;
    const int n0  = blockIdx.x * TIL;
    const int t   = threadIdx.x;     // 0..511
    const int l   = t & 63;
    const int w   = t >> 6;          // 8 waves
    const int l15 = l & 15;
    const int l4  = l >> 4;

    if (t < Cch) bos[t] = bo[t];
    {   // Wo bf16: 2048 uint4 / 512 threads = 4 each
        const uint4* wg = (const uint4*)Wob;
        #pragma unroll
        for (int p = 0; p < 4; ++p) {
            const int idx = p * 512 + t;
            const int row = idx >> 3, seg = idx & 7;
            *(uint4*)&Wos[row * 72 + seg * 8] = wg[idx];
        }
    }
    if (t < 256) {   // normalize accumulated partials + pack sa tile to bf16
        const int n = t >> 2, seg = t & 3;
        const float* o0 = Op + ((size_t)(b * Nn + n0 + n)) * CPd + seg * 16;
        const float sc = C2 / Lg[(size_t)b * Nn + n0 + n];
        unsigned pk[8];
        #pragma unroll
        for (int i = 0; i < 4; ++i) {
            const float4 a = ((const float4*)o0)[i];
            pk[2 * i]     = pk_trunc(a.x * sc, a.y * sc);
            pk[2 * i + 1] = pk_trunc(a.z * sc, a.w * sc);
        }
        *(uint4*)&Sas[n * 72 + seg * 16]     = make_uint4(pk[0], pk[1], pk[2], pk[3]);
        *(uint4*)&Sas[n * 72 + seg * 16 + 8] = make_uint4(pk[4], pk[5], pk[6], pk[7]);
    }
    __syncthreads();

    short8 bfr[4][2];
    #pragma unroll
    for (int ns = 0; ns < 4; ++ns) {
        bfr[ns][0] = *(const short8*)&Sas[(16 * ns + l15) * 72 + 8 * l4];
        bfr[ns][1] = *(const short8*)&Sas[(16 * ns + l15) * 72 + 8 * l4 + 32];
    }
    const float gam = gamma[0];
    const float* xb = x + (size_t)b * Cch * Nn;
    float*       yb = y + (size_t)b * Cch * Nn;

    #pragma unroll
    for (int os2 = 0; os2 < 2; ++os2) {
        const int obase = 16 * (w + 8 * os2);     // 16 strips over 8 waves x 2
        const short8 af0 = *(const short8*)&Wos[(obase + l15) * 72 + 8 * l4];
        const short8 af1 = *(const short8*)&Wos[(obase + l15) * 72 + 8 * l4 + 32];
        #pragma unroll
        for (int ns = 0; ns < 4; ++ns) {
            f32x4 acc = (f32x4){0.f, 0.f, 0.f, 0.f};
            acc = __builtin_amdgcn_mfma_f32_16x16x32_bf16(af0, bfr[ns][0], acc, 0, 0, 0);
            acc = __builtin_amdgcn_mfma_f32_16x16x32_bf16(af1, bfr[ns][1], acc, 0, 0, 0);
            #pragma unroll
            for (int r = 0; r < 4; ++r) {
                const int o = obase + 4 * l4 + r;
                const size_t idx = (size_t)o * Nn + n0 + 16 * ns + l15;
                yb[idx] = fmaf(gam, acc[r] + bos[o], xb[idx]);
            }
        }
    }
}

// ---------------------------------------------------------------------------
extern "C" void kernel_launch(void* const* d_in, const int* in_sizes, int n_in,
                              void* d_out, int out_size, void* d_ws, size_t ws_size,
                              hipStream_t stream)
{
    (void)in_sizes; (void)n_in; (void)out_size; (void)ws_size;
    const float* x     = (const float*)d_in[0];
    const float* Wq    = (const float*)d_in[1];
    const float* bq    = (const float*)d_in[2];
    const float* Wk    = (const float*)d_in[3];
    const float* bk    = (const float*)d_in[4];
    const float* Wv    = (const float*)d_in[5];
    const float* bv    = (const float*)d_in[6];
    const float* Wo    = (const float*)d_in[7];
    const float* bo    = (const float*)d_in[8];
    const float* gamma = (const float*)d_in[9];
    float* y = (float*)d_out;

    const size_t per = (size_t)Bsz * Nn * CPd;           // 2,097,152 elements
    unsigned short* qT = (unsigned short*)d_ws;          // 4 MB
    unsigned short* kT = qT + per;                       // 4 MB
    unsigned short* vB = kT + per;                       // 4 MB
    float* Op = (float*)(vB + per);                      // 8 MB: [b][n][c'] f32 accum
    float* Lg = Op + per;                                // 128 KB: [b][n] f32 accum
    unsigned short* Wb = (unsigned short*)(Lg + (size_t)Bsz * Nn);  // 128 KB

    // zero the atomically-accumulated partials (Op + Lg are contiguous)
    hipMemsetAsync(Op, 0, (per + (size_t)Bsz * Nn) * sizeof(float), stream);

    dim3 grid(Nn / TIL, Bsz);
    dim3 gridF(Nn / QROWS, Bsz, NSPL);
    wconv_kernel<<<64, 256, 0, stream>>>(Wq, Wk, Wv, Wo, Wb);
    qkv_kernel<<<grid, 256, 0, stream>>>(x, Wb, bq, bk, bv, qT, kT, vB);
    flash_kernel<<<gridF, 512, 0, stream>>>(qT, kT, vB, Op, Lg);
    out_kernel<<<grid, 512, 0, stream>>>(Op, Lg, Wb + 3 * 16384, bo, gamma, x, y);
}